// Round 1
// baseline (9701.670 us; speedup 1.0000x reference)
//
#include <hip/hip_runtime.h>
#include <math.h>

// Sizes (fixed by the problem)
#define NROI 512
#define CDIM 256
#define TENC 32
#define TDEC 25
#define VOCC 97

__device__ __forceinline__ float sigmoidf_(float x){ return 1.f/(1.f+__expf(-x)); }

// ---------------------------------------------------------------------------
// Generic tiled GEMM: C[M,N] = act(A[M,K] @ B[N,K]^T + bias[N] + addend[M,N])
// Block 256 threads, 64x64 tile, 4x4 per thread, BK=16.
// Requires: M % 64 == 0, K % 16 == 0. N arbitrary (guarded).
// ---------------------------------------------------------------------------
template<int ACT>
__global__ void gemm_k(const float* __restrict__ A, const float* __restrict__ B,
                       const float* __restrict__ bias, const float* __restrict__ addend,
                       float* __restrict__ Cmat, int M, int N, int K)
{
    __shared__ float As[16][68];
    __shared__ float Bs[16][68];
    const int bm = blockIdx.y * 64, bn = blockIdx.x * 64;
    const int tid = threadIdx.x;
    const int tr = tid >> 4, tc = tid & 15;
    float acc[4][4] = {};
    for (int k0 = 0; k0 < K; k0 += 16) {
        #pragma unroll
        for (int i = 0; i < 4; i++) {
            int e = tid + i * 256;          // 0..1023
            int r = e >> 4, cc = e & 15;
            As[cc][r] = A[(size_t)(bm + r) * K + k0 + cc];
            Bs[cc][r] = (bn + r < N) ? B[(size_t)(bn + r) * K + k0 + cc] : 0.f;
        }
        __syncthreads();
        #pragma unroll
        for (int kk = 0; kk < 16; kk++) {
            float a[4], b[4];
            #pragma unroll
            for (int i = 0; i < 4; i++) a[i] = As[kk][tr * 4 + i];
            #pragma unroll
            for (int j = 0; j < 4; j++) b[j] = Bs[kk][tc * 4 + j];
            #pragma unroll
            for (int i = 0; i < 4; i++)
                #pragma unroll
                for (int j = 0; j < 4; j++)
                    acc[i][j] += a[i] * b[j];
        }
        __syncthreads();
    }
    #pragma unroll
    for (int i = 0; i < 4; i++) {
        #pragma unroll
        for (int j = 0; j < 4; j++) {
            int r = bm + tr * 4 + i, c = bn + tc * 4 + j;
            if (c < N) {
                float v = acc[i][j];
                if (bias)   v += bias[c];
                if (addend) v += addend[(size_t)r * N + c];
                if (ACT == 1) v = fmaxf(v, 0.f);
                Cmat[(size_t)r * N + c] = v;
            }
        }
    }
}

// ---------------------------------------------------------------------------
// Conv 3x3, stride (2,1), pad (1,1) as im2col-on-the-fly GEMM.
// in:  (512, 256, Hin, 32) NCHW      w: (256, 256, 3, 3) -> B[co, k], k=ci*9+kh*3+kw
// out: (512, 256, Hout, 32) NCHW     M = 512*Hout*32 (row = (n,ho,wo), wo fastest)
// ---------------------------------------------------------------------------
__global__ void conv_gemm_k(const float* __restrict__ in, const float* __restrict__ w,
                            float* __restrict__ out, int Hin, int Hout)
{
    __shared__ float As[16][68];
    __shared__ float Bs[16][68];
    const int bm = blockIdx.y * 64, bn = blockIdx.x * 64;
    const int tid = threadIdx.x;
    const int tr = tid >> 4, tc = tid & 15;
    float acc[4][4] = {};
    for (int k0 = 0; k0 < 2304; k0 += 16) {
        #pragma unroll
        for (int i = 0; i < 4; i++) {
            int e = tid + i * 256;
            int r = e >> 4, cc = e & 15;
            int row = bm + r;
            int wo = row & 31;
            int ho = (row >> 5) % Hout;
            int n  = row / (32 * Hout);
            int k  = k0 + cc;
            int ci = k / 9, rem = k - ci * 9;
            int kh = rem / 3, kw = rem - kh * 3;
            int hi = ho * 2 - 1 + kh, wi = wo - 1 + kw;
            float v = 0.f;
            if ((unsigned)hi < (unsigned)Hin && (unsigned)wi < 32u)
                v = in[(((size_t)n * 256 + ci) * Hin + hi) * 32 + wi];
            As[cc][r] = v;
            Bs[cc][r] = w[(size_t)(bn + r) * 2304 + k];
        }
        __syncthreads();
        #pragma unroll
        for (int kk = 0; kk < 16; kk++) {
            float a[4], b[4];
            #pragma unroll
            for (int i = 0; i < 4; i++) a[i] = As[kk][tr * 4 + i];
            #pragma unroll
            for (int j = 0; j < 4; j++) b[j] = Bs[kk][tc * 4 + j];
            #pragma unroll
            for (int i = 0; i < 4; i++)
                #pragma unroll
                for (int j = 0; j < 4; j++)
                    acc[i][j] += a[i] * b[j];
        }
        __syncthreads();
    }
    #pragma unroll
    for (int i = 0; i < 4; i++) {
        #pragma unroll
        for (int j = 0; j < 4; j++) {
            int row = bm + tr * 4 + i, co = bn + tc * 4 + j;
            int wo = row & 31;
            int ho = (row >> 5) % Hout;
            int n  = row / (32 * Hout);
            out[(((size_t)n * 256 + co) * Hout + ho) * 32 + wo] = acc[i][j];
        }
    }
}

// ---------------------------------------------------------------------------
// Fused GroupNorm (32 groups of 8 channels) + ReLU, in-place.
// One block (256 thr) per (n, group); group data is contiguous: 8*HW floats.
// ---------------------------------------------------------------------------
__global__ void gn_relu_k(float* __restrict__ x, const float* __restrict__ s,
                          const float* __restrict__ b, int HW)
{
    const int blk = blockIdx.x;          // n*32 + g
    const int len = 8 * HW;
    float* p = x + (size_t)blk * len;
    const int g = blk & 31;
    float sum = 0.f, sq = 0.f;
    for (int i = threadIdx.x; i < len; i += 256) { float v = p[i]; sum += v; sq += v * v; }
    __shared__ float rs[8], rq[8];
    for (int o = 32; o > 0; o >>= 1) { sum += __shfl_down(sum, o); sq += __shfl_down(sq, o); }
    int wid = threadIdx.x >> 6, lane = threadIdx.x & 63;
    if (lane == 0) { rs[wid] = sum; rq[wid] = sq; }
    __syncthreads();
    if (threadIdx.x == 0) {
        float S = rs[0] + rs[1] + rs[2] + rs[3];
        float Q = rq[0] + rq[1] + rq[2] + rq[3];
        float mu = S / len;
        float var = Q / len - mu * mu;
        rs[4] = mu; rq[4] = rsqrtf(var + 1e-5f);
    }
    __syncthreads();
    float mu = rs[4], rstd = rq[4];
    for (int i = threadIdx.x; i < len; i += 256) {
        int c = g * 8 + i / HW;
        float v = (p[i] - mu) * rstd * s[c] + b[c];
        p[i] = fmaxf(v, 0.f);
    }
}

// x2 (512,256,2,32) --mean over H, transpose--> xT (32,512,256)
__global__ void pool_tr_k(const float* __restrict__ x2, float* __restrict__ xT)
{
    int idx = blockIdx.x * 256 + threadIdx.x;   // 32*512*256 = 4,194,304
    int c = idx & 255; int n = (idx >> 8) & 511; int t = idx >> 17;
    const float* q = x2 + (((size_t)n * 256 + c) * 2) * 32 + t;
    xT[idx] = 0.5f * (q[0] + q[32]);
}

__global__ void addvec_k(const float* __restrict__ a, const float* __restrict__ b,
                         float* __restrict__ o, int n)
{
    int i = blockIdx.x * 256 + threadIdx.x;
    if (i < n) o[i] = a[i] + b[i];
}

// gates (512,1024) [i,f,g,o]; h,c (512,256); hout row-stride 512 (concat buffer)
__global__ void lstm_cell_k(const float* __restrict__ g, float* __restrict__ h,
                            float* __restrict__ c, float* __restrict__ hout)
{
    int idx = blockIdx.x * 256 + threadIdx.x;   // 131072
    int n = idx >> 8, cc = idx & 255;
    const float* gr = g + (size_t)n * 1024;
    float i_ = sigmoidf_(gr[cc]);
    float f_ = sigmoidf_(gr[256 + cc]);
    float g_ = tanhf(gr[512 + cc]);
    float o_ = sigmoidf_(gr[768 + cc]);
    float cn = f_ * c[idx] + i_ * g_;
    c[idx] = cn;
    float hn = o_ * tanhf(cn);
    h[idx] = hn;
    hout[(size_t)n * 512 + cc] = hn;
}

// scores[t,n] = sum_c tanh(h[n,c]+enc[t,n,c])*vw[c] + vb ; one wave per (t,n)
__global__ void att_score_k(const float* __restrict__ h, const float* __restrict__ enc,
                            const float* __restrict__ vw, const float* __restrict__ vb,
                            float* __restrict__ scores)
{
    int w = threadIdx.x >> 6, lane = threadIdx.x & 63;
    int out = blockIdx.x * 4 + w;               // 0..16383 = t*512+n
    const float* hp = h + (size_t)(out & 511) * 256;
    const float* ep = enc + (size_t)out * 256;
    float s = 0.f;
    #pragma unroll
    for (int j = 0; j < 4; j++) {
        int c = lane + j * 64;
        s += tanhf(hp[c] + ep[c]) * vw[c];
    }
    for (int o = 32; o > 0; o >>= 1) s += __shfl_down(s, o);
    if (lane == 0) scores[out] = s + vb[0];
}

// softmax over t (32) for each n (512); scores/aw layout (32,512)
__global__ void softmax_t_k(const float* __restrict__ scores, float* __restrict__ aw)
{
    int n = blockIdx.x * 256 + threadIdx.x;
    if (n >= 512) return;
    float v[32]; float m = -1e30f;
    #pragma unroll
    for (int t = 0; t < 32; t++) { v[t] = scores[t * 512 + n]; m = fmaxf(m, v[t]); }
    float s = 0.f;
    #pragma unroll
    for (int t = 0; t < 32; t++) { v[t] = __expf(v[t] - m); s += v[t]; }
    float inv = 1.f / s;
    #pragma unroll
    for (int t = 0; t < 32; t++) aw[t * 512 + n] = v[t] * inv;
}

// ctx[n,c] = sum_t aw[t,n]*enc[t,n,c]
__global__ void ctx_k(const float* __restrict__ aw, const float* __restrict__ enc,
                      float* __restrict__ ctx)
{
    int n = blockIdx.x, c = threadIdx.x;
    float s = 0.f;
    #pragma unroll
    for (int t = 0; t < 32; t++)
        s += aw[t * 512 + n] * enc[((size_t)t * 512 + n) * 256 + c];
    ctx[n * 256 + c] = s;
}

// xcat[n, 0:256] = att_emb[tok[n]]; xcat[n, 256:512] = ctx[n]
__global__ void xcat_k(const int* __restrict__ targets, const float* __restrict__ att_emb,
                       const float* __restrict__ ctx, float* __restrict__ xcat, int t)
{
    int idx = blockIdx.x * 256 + threadIdx.x;   // 262144
    int n = idx >> 9, k = idx & 511;
    int tok = (t == 0) ? 0 : targets[n * TDEC + t - 1];
    xcat[idx] = (k < 256) ? att_emb[(size_t)tok * 256 + k] : ctx[n * 256 + (k - 256)];
}

// GRU cell: gi,gh (512,768) [r,z,n]; h (512,256) updated in place
__global__ void gru_cell_k(const float* __restrict__ gi, const float* __restrict__ gh,
                           float* __restrict__ h)
{
    int idx = blockIdx.x * 256 + threadIdx.x;   // 131072
    int n = idx >> 8, cc = idx & 255;
    const float* a = gi + (size_t)n * 768;
    const float* b = gh + (size_t)n * 768;
    float r  = sigmoidf_(a[cc] + b[cc]);
    float z  = sigmoidf_(a[256 + cc] + b[256 + cc]);
    float ng = tanhf(a[512 + cc] + r * b[512 + cc]);
    h[idx] = (1.f - z) * ng + z * h[idx];
}

// NLL over log_softmax rows; accumulate mean into out[0] (write at t==0)
__global__ void loss_k(const float* __restrict__ logits, const int* __restrict__ targets,
                       float* __restrict__ out, int t)
{
    __shared__ float red[512];
    int n = threadIdx.x;                         // 512 threads, 1 block
    const float* row = logits + (size_t)n * VOCC;
    float m = -1e30f;
    for (int j = 0; j < VOCC; j++) m = fmaxf(m, row[j]);
    float s = 0.f;
    for (int j = 0; j < VOCC; j++) s += expf(row[j] - m);
    int tg = targets[n * TDEC + t];
    red[n] = m + logf(s) - row[tg];
    __syncthreads();
    for (int o = 256; o > 0; o >>= 1) { if (n < o) red[n] += red[n + o]; __syncthreads(); }
    if (n == 0) {
        float sl = red[0] / 512.f;
        if (t == 0) out[0] = sl; else out[0] += sl;
    }
}

extern "C" void kernel_launch(void* const* d_in, const int* in_sizes, int n_in,
                              void* d_out, int out_size, void* d_ws, size_t ws_size,
                              hipStream_t stream)
{
    const float* rois     = (const float*)d_in[0];
    const int*   targets  = (const int*)  d_in[1];
    const float* conv1_w  = (const float*)d_in[2];
    const float* gn1_s    = (const float*)d_in[3];
    const float* gn1_b    = (const float*)d_in[4];
    const float* conv2_w  = (const float*)d_in[5];
    const float* gn2_s    = (const float*)d_in[6];
    const float* gn2_b    = (const float*)d_in[7];
    const float* wih_f    = (const float*)d_in[8];
    const float* whh_f    = (const float*)d_in[9];
    const float* bih_f    = (const float*)d_in[10];
    const float* bhh_f    = (const float*)d_in[11];
    const float* wih_b    = (const float*)d_in[12];
    const float* whh_b    = (const float*)d_in[13];
    const float* bih_b    = (const float*)d_in[14];
    const float* bhh_b    = (const float*)d_in[15];
    const float* emb_w    = (const float*)d_in[16];
    const float* emb_b    = (const float*)d_in[17];
    const float* att_emb  = (const float*)d_in[18];
    const float* comb_w   = (const float*)d_in[19];
    const float* comb_b   = (const float*)d_in[20];
    const float* gru_wih  = (const float*)d_in[21];
    const float* gru_whh  = (const float*)d_in[22];
    const float* gru_bih  = (const float*)d_in[23];
    const float* gru_bhh  = (const float*)d_in[24];
    const float* out_w    = (const float*)d_in[25];
    const float* out_b    = (const float*)d_in[26];
    const float* vat_w    = (const float*)d_in[27];
    const float* vat_b    = (const float*)d_in[28];

    float* ws = (float*)d_ws;
    // Workspace layout (floats); total = 35,867,136 floats = 143.5 MB
    float* A_     = ws;                 // 16,777,216 : x1 (512,256,4,32) then LSTM gates (32,512,1024)
    float* B_     = ws + 16777216;      //  8,388,608 : x2 (512,256,2,32) then hcat (32,512,512)
    float* xT     = ws + 25165824;      //  4,194,304 : (32,512,256)
    float* enc    = ws + 29360128;      //  4,194,304 : (32,512,256)
    float* ghb    = ws + 33554432;      //    524,288 : LSTM step gates (512,1024)
    float* hS     = ws + 34078720;      //    131,072
    float* cS     = ws + 34209792;      //    131,072
    float* hdec   = ws + 34340864;      //    131,072
    float* scores = ws + 34471936;      //     16,384
    float* aw     = ws + 34488320;      //     16,384
    float* ctxb   = ws + 34504704;      //    131,072
    float* xcat   = ws + 34635776;      //    262,144
    float* xin    = ws + 34897920;      //    131,072
    float* gi     = ws + 35028992;      //    393,216
    float* ghd    = ws + 35422208;      //    393,216
    float* logits = ws + 35815424;      //     49,664
    float* bias2f = ws + 35865088;      //      1,024
    float* bias2b = ws + 35866112;      //      1,024

    dim3 blk(256);

    // ---- CRNN encoder ----
    conv_gemm_k<<<dim3(4, 1024), blk, 0, stream>>>(rois, conv1_w, A_, 8, 4);
    gn_relu_k<<<16384, blk, 0, stream>>>(A_, gn1_s, gn1_b, 128);
    conv_gemm_k<<<dim3(4, 512), blk, 0, stream>>>(A_, conv2_w, B_, 4, 2);
    gn_relu_k<<<16384, blk, 0, stream>>>(B_, gn2_s, gn2_b, 64);
    pool_tr_k<<<16384, blk, 0, stream>>>(B_, xT);

    addvec_k<<<4, blk, 0, stream>>>(bih_f, bhh_f, bias2f, 1024);
    addvec_k<<<4, blk, 0, stream>>>(bih_b, bhh_b, bias2b, 1024);

    // ---- forward LSTM ----
    gemm_k<0><<<dim3(16, 256), blk, 0, stream>>>(xT, wih_f, bias2f, nullptr, A_, 16384, 1024, 256);
    hipMemsetAsync(hS, 0, 131072 * 4, stream);
    hipMemsetAsync(cS, 0, 131072 * 4, stream);
    for (int t = 0; t < TENC; t++) {
        gemm_k<0><<<dim3(16, 8), blk, 0, stream>>>(hS, whh_f, nullptr, A_ + (size_t)t * 524288,
                                                   ghb, 512, 1024, 256);
        lstm_cell_k<<<512, blk, 0, stream>>>(ghb, hS, cS, B_ + (size_t)t * 262144);
    }
    // ---- backward LSTM ----
    gemm_k<0><<<dim3(16, 256), blk, 0, stream>>>(xT, wih_b, bias2b, nullptr, A_, 16384, 1024, 256);
    hipMemsetAsync(hS, 0, 131072 * 4, stream);
    hipMemsetAsync(cS, 0, 131072 * 4, stream);
    for (int t = TENC - 1; t >= 0; t--) {
        gemm_k<0><<<dim3(16, 8), blk, 0, stream>>>(hS, whh_b, nullptr, A_ + (size_t)t * 524288,
                                                   ghb, 512, 1024, 256);
        lstm_cell_k<<<512, blk, 0, stream>>>(ghb, hS, cS, B_ + (size_t)t * 262144 + 256);
    }
    // enc = hcat @ emb_w.T + emb_b
    gemm_k<0><<<dim3(4, 256), blk, 0, stream>>>(B_, emb_w, emb_b, nullptr, enc, 16384, 256, 512);

    // ---- attention GRU decoder ----
    hipMemsetAsync(hdec, 0, 131072 * 4, stream);
    float* out = (float*)d_out;
    for (int t = 0; t < TDEC; t++) {
        att_score_k<<<4096, blk, 0, stream>>>(hdec, enc, vat_w, vat_b, scores);
        softmax_t_k<<<2, blk, 0, stream>>>(scores, aw);
        ctx_k<<<512, blk, 0, stream>>>(aw, enc, ctxb);
        xcat_k<<<1024, blk, 0, stream>>>(targets, att_emb, ctxb, xcat, t);
        gemm_k<1><<<dim3(4, 8), blk, 0, stream>>>(xcat, comb_w, comb_b, nullptr, xin, 512, 256, 512);
        gemm_k<0><<<dim3(12, 8), blk, 0, stream>>>(xin, gru_wih, gru_bih, nullptr, gi, 512, 768, 256);
        gemm_k<0><<<dim3(12, 8), blk, 0, stream>>>(hdec, gru_whh, gru_bhh, nullptr, ghd, 512, 768, 256);
        gru_cell_k<<<512, blk, 0, stream>>>(gi, ghd, hdec);
        gemm_k<0><<<dim3(2, 8), blk, 0, stream>>>(hdec, out_w, out_b, nullptr, logits, 512, VOCC, 256);
        loss_k<<<1, dim3(512), 0, stream>>>(logits, targets, out, t);
    }
}

// Round 2
// 5722.301 us; speedup vs baseline: 1.6954x; 1.6954x over previous
//
#include <hip/hip_runtime.h>
#include <math.h>

#define NROI 512
#define CDIM 256
#define TENC 32
#define TDEC 25
#define VOCC 97

typedef unsigned short ushort_t;
typedef __attribute__((ext_vector_type(8))) short short8v;
typedef __attribute__((ext_vector_type(4))) float float4v;

__device__ __forceinline__ float sigmoidf_(float x){ return 1.f/(1.f+__expf(-x)); }
__device__ __forceinline__ ushort_t f2b(float f){
    unsigned u = __float_as_uint(f);
    u = u + 0x7fffu + ((u >> 16) & 1u);
    return (ushort_t)(u >> 16);
}
__device__ __forceinline__ float b2f(ushort_t h){
    return __uint_as_float(((unsigned)h) << 16);
}

// float -> bf16 convert
__global__ void f2b_k(const float* __restrict__ s, ushort_t* __restrict__ d, int n)
{
    int i = blockIdx.x * 256 + threadIdx.x;
    if (i < n) d[i] = f2b(s[i]);
}

// ---------------------------------------------------------------------------
// MFMA bf16 GEMM: C[M,N] = A[M,K] @ B[N,K]^T (+bias) (+bf16 addend)
// 128x128 tile, 256 threads (4 waves 2x2), BK=32, double-buffered regs.
// M,N multiples of 128; K multiple of 64.
// Row-half split: blocks with bm >= rowsplit use Bb / addb (rows rebased).
// ---------------------------------------------------------------------------
template<int OUTBF, int ADDBF>
__global__ void __launch_bounds__(256)
mgemm_k(const ushort_t* __restrict__ A, const ushort_t* __restrict__ Ba,
        const ushort_t* __restrict__ Bb, const float* __restrict__ bias,
        const ushort_t* __restrict__ adda, const ushort_t* __restrict__ addb,
        void* __restrict__ Cout, int M, int N, int K, int rowsplit)
{
    __shared__ ushort_t As[128 * 32];
    __shared__ ushort_t Bs[128 * 32];
    const int tid = threadIdx.x;
    const int lane = tid & 63, wid = tid >> 6;
    const int wr = wid >> 1, wc = wid & 1;
    const int bm = blockIdx.y * 128, bn = blockIdx.x * 128;
    const ushort_t* Bp = (bm < rowsplit) ? Ba : Bb;

    const int ch0 = tid, ch1 = tid + 256;
    const int r0 = ch0 >> 2, c0 = ch0 & 3;
    const int r1 = ch1 >> 2, c1 = ch1 & 3;
    const size_t Ar0 = (size_t)(bm + r0) * K, Ar1 = (size_t)(bm + r1) * K;
    const size_t Br0 = (size_t)(bn + r0) * K, Br1 = (size_t)(bn + r1) * K;

    float4v acc[4][4];
    #pragma unroll
    for (int m = 0; m < 4; m++)
        #pragma unroll
        for (int n = 0; n < 4; n++) { float4v z = {0.f,0.f,0.f,0.f}; acc[m][n] = z; }

    short8v ra[2][2], rb[2][2];
    auto LOAD = [&](int b, int k0) {
        ra[b][0] = *(const short8v*)&A [Ar0 + k0 + c0 * 8];
        ra[b][1] = *(const short8v*)&A [Ar1 + k0 + c1 * 8];
        rb[b][0] = *(const short8v*)&Bp[Br0 + k0 + c0 * 8];
        rb[b][1] = *(const short8v*)&Bp[Br1 + k0 + c1 * 8];
    };
    auto STORE = [&](int b) {
        *(short8v*)&As[ch0 * 8] = ra[b][0];
        *(short8v*)&As[ch1 * 8] = ra[b][1];
        *(short8v*)&Bs[ch0 * 8] = rb[b][0];
        *(short8v*)&Bs[ch1 * 8] = rb[b][1];
    };
    const int lr = lane & 15, lk = lane >> 4;
    auto COMPUTE = [&]() {
        short8v af[4], bf[4];
        #pragma unroll
        for (int m = 0; m < 4; m++)
            af[m] = *(const short8v*)&As[(wr * 64 + m * 16 + lr) * 32 + lk * 8];
        #pragma unroll
        for (int n = 0; n < 4; n++)
            bf[n] = *(const short8v*)&Bs[(wc * 64 + n * 16 + lr) * 32 + lk * 8];
        #pragma unroll
        for (int m = 0; m < 4; m++)
            #pragma unroll
            for (int n = 0; n < 4; n++)
                acc[m][n] = __builtin_amdgcn_mfma_f32_16x16x32_bf16(af[m], bf[n], acc[m][n], 0, 0, 0);
    };

    LOAD(0, 0);
    for (int k0 = 0; k0 < K; k0 += 64) {
        __syncthreads();
        STORE(0);
        __syncthreads();
        LOAD(1, k0 + 32);
        COMPUTE();
        __syncthreads();
        STORE(1);
        __syncthreads();
        if (k0 + 64 < K) LOAD(0, k0 + 64);
        COMPUTE();
    }

    const ushort_t* add = (bm < rowsplit) ? adda : addb;
    const int roff = (bm < rowsplit) ? 0 : rowsplit;
    #pragma unroll
    for (int m = 0; m < 4; m++)
        #pragma unroll
        for (int n = 0; n < 4; n++)
            #pragma unroll
            for (int r = 0; r < 4; r++) {
                int row = bm + wr * 64 + m * 16 + lk * 4 + r;
                int col = bn + wc * 64 + n * 16 + lr;
                float v = acc[m][n][r];
                if (bias) v += bias[col];
                if (ADDBF) v += b2f(add[(size_t)(row - roff) * N + col]);
                if (OUTBF) ((ushort_t*)Cout)[(size_t)row * N + col] = f2b(v);
                else       ((float*)   Cout)[(size_t)row * N + col] = v;
            }
}

// ---------------------------------------------------------------------------
// Conv 3x3 stride(2,1) pad(1,1) as MFMA GEMM with im2col-on-the-fly A gather.
// in fp32 NCHW (512,256,Hin,32); w bf16 [co][k], k = ci*9+kh*3+kw; out fp32 NCHW.
// M = 512*Hout*32 (row=(n,ho,wo), wo fastest), N = 256, K = 2304.
// ---------------------------------------------------------------------------
__global__ void __launch_bounds__(256)
cgemm_k(const float* __restrict__ in, const ushort_t* __restrict__ wbf,
        float* __restrict__ out, int Hin, int Hout)
{
    const int K = 2304;
    __shared__ ushort_t As[128 * 32];
    __shared__ ushort_t Bs[128 * 32];
    const int tid = threadIdx.x;
    const int lane = tid & 63, wid = tid >> 6;
    const int wr = wid >> 1, wc = wid & 1;
    const int bm = blockIdx.y * 128, bn = blockIdx.x * 128;

    // A gather: each thread owns row (tid>>1), k-half (tid&1)*16
    const int arow = bm + (tid >> 1);
    const int wo = arow & 31, ho = (arow >> 5) % Hout, nimg = arow / (32 * Hout);
    const float* base = in + (size_t)nimg * 256 * Hin * 32;
    const int khalf = (tid & 1) * 16;

    // B staging chunks
    const int ch0 = tid, ch1 = tid + 256;
    const int r0 = ch0 >> 2, c0 = ch0 & 3;
    const int r1 = ch1 >> 2, c1 = ch1 & 3;
    const size_t Br0 = (size_t)(bn + r0) * K, Br1 = (size_t)(bn + r1) * K;

    float4v acc[4][4];
    #pragma unroll
    for (int m = 0; m < 4; m++)
        #pragma unroll
        for (int n = 0; n < 4; n++) { float4v z = {0.f,0.f,0.f,0.f}; acc[m][n] = z; }

    float fA[2][16];
    short8v rb[2][2];
    auto LOAD = [&](int b, int k0) {
        #pragma unroll
        for (int kk = 0; kk < 16; kk++) {
            int k = k0 + khalf + kk;
            int ci = k / 9; int rem = k - ci * 9;
            int kh = rem / 3; int kw = rem - kh * 3;
            int hi = ho * 2 - 1 + kh, wi = wo - 1 + kw;
            float v = 0.f;
            if ((unsigned)hi < (unsigned)Hin && (unsigned)wi < 32u)
                v = base[((size_t)ci * Hin + hi) * 32 + wi];
            fA[b][kk] = v;
        }
        rb[b][0] = *(const short8v*)&wbf[Br0 + k0 + c0 * 8];
        rb[b][1] = *(const short8v*)&wbf[Br1 + k0 + c1 * 8];
    };
    auto STORE = [&](int b) {
        union { short8v v; ushort_t u[8]; } p0, p1;
        #pragma unroll
        for (int j = 0; j < 8; j++) { p0.u[j] = f2b(fA[b][j]); p1.u[j] = f2b(fA[b][8 + j]); }
        *(short8v*)&As[(tid >> 1) * 32 + khalf]     = p0.v;
        *(short8v*)&As[(tid >> 1) * 32 + khalf + 8] = p1.v;
        *(short8v*)&Bs[ch0 * 8] = rb[b][0];
        *(short8v*)&Bs[ch1 * 8] = rb[b][1];
    };
    const int lr = lane & 15, lk = lane >> 4;
    auto COMPUTE = [&]() {
        short8v af[4], bf[4];
        #pragma unroll
        for (int m = 0; m < 4; m++)
            af[m] = *(const short8v*)&As[(wr * 64 + m * 16 + lr) * 32 + lk * 8];
        #pragma unroll
        for (int n = 0; n < 4; n++)
            bf[n] = *(const short8v*)&Bs[(wc * 64 + n * 16 + lr) * 32 + lk * 8];
        #pragma unroll
        for (int m = 0; m < 4; m++)
            #pragma unroll
            for (int n = 0; n < 4; n++)
                acc[m][n] = __builtin_amdgcn_mfma_f32_16x16x32_bf16(af[m], bf[n], acc[m][n], 0, 0, 0);
    };

    LOAD(0, 0);
    for (int k0 = 0; k0 < K; k0 += 64) {
        __syncthreads();
        STORE(0);
        __syncthreads();
        LOAD(1, k0 + 32);
        COMPUTE();
        __syncthreads();
        STORE(1);
        __syncthreads();
        if (k0 + 64 < K) LOAD(0, k0 + 64);
        COMPUTE();
    }

    #pragma unroll
    for (int m = 0; m < 4; m++)
        #pragma unroll
        for (int n = 0; n < 4; n++)
            #pragma unroll
            for (int r = 0; r < 4; r++) {
                int row = bm + wr * 64 + m * 16 + lk * 4 + r;
                int col = bn + wc * 64 + n * 16 + lr;
                int wo2 = row & 31, ho2 = (row >> 5) % Hout, n2 = row / (32 * Hout);
                out[(((size_t)n2 * 256 + col) * Hout + ho2) * 32 + wo2] = acc[m][n][r];
            }
}

// ---------------------------------------------------------------------------
// GroupNorm(32 groups of 8 ch) + ReLU, in-place, fp32 NCHW.
// ---------------------------------------------------------------------------
__global__ void gn_relu_k(float* __restrict__ x, const float* __restrict__ s,
                          const float* __restrict__ b, int HW)
{
    const int blk = blockIdx.x;
    const int len = 8 * HW;
    float* p = x + (size_t)blk * len;
    const int g = blk & 31;
    float sum = 0.f, sq = 0.f;
    for (int i = threadIdx.x; i < len; i += 256) { float v = p[i]; sum += v; sq += v * v; }
    __shared__ float rs[8], rq[8];
    for (int o = 32; o > 0; o >>= 1) { sum += __shfl_down(sum, o); sq += __shfl_down(sq, o); }
    int wid = threadIdx.x >> 6, lane = threadIdx.x & 63;
    if (lane == 0) { rs[wid] = sum; rq[wid] = sq; }
    __syncthreads();
    if (threadIdx.x == 0) {
        float S = rs[0] + rs[1] + rs[2] + rs[3];
        float Q = rq[0] + rq[1] + rq[2] + rq[3];
        float mu = S / len;
        float var = Q / len - mu * mu;
        rs[4] = mu; rq[4] = rsqrtf(var + 1e-5f);
    }
    __syncthreads();
    float mu = rs[4], rstd = rq[4];
    for (int i = threadIdx.x; i < len; i += 256) {
        int c = g * 8 + i / HW;
        float v = (p[i] - mu) * rstd * s[c] + b[c];
        p[i] = fmaxf(v, 0.f);
    }
}

// x2 fp32 (512,256,2,32) --mean over H, transpose--> xT bf16 (32,512,256)
__global__ void pool_tr_k(const float* __restrict__ x2, ushort_t* __restrict__ xT)
{
    int idx = blockIdx.x * 256 + threadIdx.x;
    int c = idx & 255; int n = (idx >> 8) & 511; int t = idx >> 17;
    const float* q = x2 + (((size_t)n * 256 + c) * 2) * 32 + t;
    xT[idx] = f2b(0.5f * (q[0] + q[32]));
}

__global__ void addvec_k(const float* __restrict__ a, const float* __restrict__ b,
                         float* __restrict__ o, int n)
{
    int i = blockIdx.x * 256 + threadIdx.x;
    if (i < n) o[i] = a[i] + b[i];
}

// Merged fwd/bwd LSTM cell. ghb (1024,1024) fp32: rows 0-511 fwd@t, 512-1023 bwd@31-t.
__global__ void lstm2_cell_k(const float* __restrict__ g, float* __restrict__ cS,
                             ushort_t* __restrict__ hbf, ushort_t* __restrict__ hcat, int t)
{
    int idx = blockIdx.x * 256 + threadIdx.x;       // 262144
    int n2 = idx >> 8, cc = idx & 255;
    const float* gr = g + (size_t)n2 * 1024;
    float i_ = sigmoidf_(gr[cc]);
    float f_ = sigmoidf_(gr[256 + cc]);
    float g_ = tanhf(gr[512 + cc]);
    float o_ = sigmoidf_(gr[768 + cc]);
    float cn = f_ * cS[idx] + i_ * g_;
    cS[idx] = cn;
    float hn = o_ * tanhf(cn);
    ushort_t hb = f2b(hn);
    hbf[idx] = hb;
    if (n2 < 512) hcat[((size_t)t * 512 + n2) * 512 + cc] = hb;
    else          hcat[((size_t)(31 - t) * 512 + (n2 - 512)) * 512 + 256 + cc] = hb;
}

// ---------------------------------------------------------------------------
// fp32 tiled GEMM (decoder small mats): C = act(A@B^T + bias), 64x64 tile.
// ---------------------------------------------------------------------------
template<int ACT>
__device__ __forceinline__ void gemm_body(const float* __restrict__ A, const float* __restrict__ B,
                                          const float* __restrict__ bias, float* __restrict__ Cmat,
                                          int bx, int by, int M, int N, int K)
{
    __shared__ float As[16][68];
    __shared__ float Bs[16][68];
    const int bm = by * 64, bn = bx * 64;
    const int tid = threadIdx.x;
    const int tr = tid >> 4, tc = tid & 15;
    float acc[4][4] = {};
    for (int k0 = 0; k0 < K; k0 += 16) {
        #pragma unroll
        for (int i = 0; i < 4; i++) {
            int e = tid + i * 256;
            int r = e >> 4, cc = e & 15;
            As[cc][r] = A[(size_t)(bm + r) * K + k0 + cc];
            Bs[cc][r] = (bn + r < N) ? B[(size_t)(bn + r) * K + k0 + cc] : 0.f;
        }
        __syncthreads();
        #pragma unroll
        for (int kk = 0; kk < 16; kk++) {
            float a[4], b[4];
            #pragma unroll
            for (int i = 0; i < 4; i++) a[i] = As[kk][tr * 4 + i];
            #pragma unroll
            for (int j = 0; j < 4; j++) b[j] = Bs[kk][tc * 4 + j];
            #pragma unroll
            for (int i = 0; i < 4; i++)
                #pragma unroll
                for (int j = 0; j < 4; j++)
                    acc[i][j] += a[i] * b[j];
        }
        __syncthreads();
    }
    #pragma unroll
    for (int i = 0; i < 4; i++)
        #pragma unroll
        for (int j = 0; j < 4; j++) {
            int r = bm + tr * 4 + i, c = bn + tc * 4 + j;
            if (c < N) {
                float v = acc[i][j];
                if (bias) v += bias[c];
                if (ACT == 1) v = fmaxf(v, 0.f);
                Cmat[(size_t)r * N + c] = v;
            }
        }
}

template<int ACT>
__global__ void gemm_k(const float* __restrict__ A, const float* __restrict__ B,
                       const float* __restrict__ bias, float* __restrict__ Cmat,
                       int M, int N, int K)
{
    gemm_body<ACT>(A, B, bias, Cmat, blockIdx.x, blockIdx.y, M, N, K);
}

// gi/gh in one launch via blockIdx.z (both M=512,N=768,K=256)
__global__ void gemmz_k(const float* A0, const float* B0, const float* b0, float* C0,
                        const float* A1, const float* B1, const float* b1, float* C1)
{
    if (blockIdx.z == 0) gemm_body<0>(A0, B0, b0, C0, blockIdx.x, blockIdx.y, 512, 768, 256);
    else                 gemm_body<0>(A1, B1, b1, C1, blockIdx.x, blockIdx.y, 512, 768, 256);
}

// ---------------------------------------------------------------------------
// Fused attention: scores + softmax + ctx + xcat assembly. Block per roi n.
// ---------------------------------------------------------------------------
__global__ void att_fused_k(const float* __restrict__ hdec, const float* __restrict__ enc,
                            const float* __restrict__ vw, const float* __restrict__ vb,
                            const int* __restrict__ targets, const float* __restrict__ att_emb,
                            float* __restrict__ xcat, int t)
{
    __shared__ float encs[32][256];
    __shared__ float sc[32];
    const int n = blockIdx.x;
    const int tid = threadIdx.x, lane = tid & 63, w = tid >> 6;
    const float* hrow = hdec + n * 256;
    #pragma unroll
    for (int q = 0; q < 8; q++) {
        int tt = w * 8 + q;
        const float* ep = enc + ((size_t)tt * 512 + n) * 256;
        float s = 0.f;
        #pragma unroll
        for (int j = 0; j < 4; j++) {
            int c = lane + j * 64;
            float e = ep[c];
            encs[tt][c] = e;
            s += tanhf(hrow[c] + e) * vw[c];
        }
        for (int o = 32; o > 0; o >>= 1) s += __shfl_down(s, o);
        if (lane == 0) sc[tt] = s + vb[0];
    }
    __syncthreads();
    float m = -1e30f;
    #pragma unroll
    for (int t2 = 0; t2 < 32; t2++) m = fmaxf(m, sc[t2]);
    float sum = 0.f;
    #pragma unroll
    for (int t2 = 0; t2 < 32; t2++) sum += __expf(sc[t2] - m);
    float ctxv = 0.f;
    #pragma unroll
    for (int t2 = 0; t2 < 32; t2++) ctxv += __expf(sc[t2] - m) * encs[t2][tid];
    ctxv /= sum;
    int tok = (t == 0) ? 0 : targets[n * TDEC + t - 1];
    xcat[(size_t)n * 512 + 256 + tid] = ctxv;
    xcat[(size_t)n * 512 + tid] = att_emb[(size_t)tok * 256 + tid];
}

// GRU cell
__global__ void gru_cell_k(const float* __restrict__ gi, const float* __restrict__ gh,
                           float* __restrict__ h)
{
    int idx = blockIdx.x * 256 + threadIdx.x;
    int n = idx >> 8, cc = idx & 255;
    const float* a = gi + (size_t)n * 768;
    const float* b = gh + (size_t)n * 768;
    float r  = sigmoidf_(a[cc] + b[cc]);
    float z  = sigmoidf_(a[256 + cc] + b[256 + cc]);
    float ng = tanhf(a[512 + cc] + r * b[512 + cc]);
    h[idx] = (1.f - z) * ng + z * h[idx];
}

// NLL over log_softmax rows; accumulate mean into out[0]
__global__ void loss_k(const float* __restrict__ logits, const int* __restrict__ targets,
                       float* __restrict__ out, int t)
{
    __shared__ float red[512];
    int n = threadIdx.x;
    const float* row = logits + (size_t)n * VOCC;
    float m = -1e30f;
    for (int j = 0; j < VOCC; j++) m = fmaxf(m, row[j]);
    float s = 0.f;
    for (int j = 0; j < VOCC; j++) s += expf(row[j] - m);
    int tg = targets[n * TDEC + t];
    red[n] = m + logf(s) - row[tg];
    __syncthreads();
    for (int o = 256; o > 0; o >>= 1) { if (n < o) red[n] += red[n + o]; __syncthreads(); }
    if (n == 0) {
        float sl = red[0] / 512.f;
        if (t == 0) out[0] = sl; else out[0] += sl;
    }
}

extern "C" void kernel_launch(void* const* d_in, const int* in_sizes, int n_in,
                              void* d_out, int out_size, void* d_ws, size_t ws_size,
                              hipStream_t stream)
{
    const float* rois     = (const float*)d_in[0];
    const int*   targets  = (const int*)  d_in[1];
    const float* conv1_w  = (const float*)d_in[2];
    const float* gn1_s    = (const float*)d_in[3];
    const float* gn1_b    = (const float*)d_in[4];
    const float* conv2_w  = (const float*)d_in[5];
    const float* gn2_s    = (const float*)d_in[6];
    const float* gn2_b    = (const float*)d_in[7];
    const float* wih_f    = (const float*)d_in[8];
    const float* whh_f    = (const float*)d_in[9];
    const float* bih_f    = (const float*)d_in[10];
    const float* bhh_f    = (const float*)d_in[11];
    const float* wih_b    = (const float*)d_in[12];
    const float* whh_b    = (const float*)d_in[13];
    const float* bih_b    = (const float*)d_in[14];
    const float* bhh_b    = (const float*)d_in[15];
    const float* emb_w    = (const float*)d_in[16];
    const float* emb_b    = (const float*)d_in[17];
    const float* att_emb  = (const float*)d_in[18];
    const float* comb_w   = (const float*)d_in[19];
    const float* comb_b   = (const float*)d_in[20];
    const float* gru_wih  = (const float*)d_in[21];
    const float* gru_whh  = (const float*)d_in[22];
    const float* gru_bih  = (const float*)d_in[23];
    const float* gru_bhh  = (const float*)d_in[24];
    const float* out_w    = (const float*)d_in[25];
    const float* out_b    = (const float*)d_in[26];
    const float* vat_w    = (const float*)d_in[27];
    const float* vat_b    = (const float*)d_in[28];

    float* ws = (float*)d_ws;
    // Layout (float offsets); total 35,441,152 floats = 141.8 MB
    float*    buf0    = ws;                          // 16,777,216: x1 fp32 | later xgates bf16 (f then b)
    float*    buf1    = ws + 16777216;               //  8,388,608: x2 fp32 | later enc fp32 (4,194,304)
    ushort_t* xT_bf   = (ushort_t*)(ws + 25165824);  //  4,194,304 bf16
    ushort_t* hcat_bf = (ushort_t*)(ws + 27262976);  //  8,388,608 bf16
    float*    ghb     = ws + 31457280;               //  1,048,576
    ushort_t* hS_bf   = (ushort_t*)(ws + 32505856);  //    262,144 bf16
    float*    cS      = ws + 32636928;               //    262,144
    ushort_t* c1w_bf  = (ushort_t*)(ws + 32899072);  //    589,824 bf16
    ushort_t* c2w_bf  = (ushort_t*)(ws + 33193984);  //    589,824 bf16
    ushort_t* wihf_bf = (ushort_t*)(ws + 33488896);  //    262,144 bf16
    ushort_t* wihb_bf = (ushort_t*)(ws + 33619968);
    ushort_t* whhf_bf = (ushort_t*)(ws + 33751040);
    ushort_t* whhb_bf = (ushort_t*)(ws + 33882112);
    ushort_t* embw_bf = (ushort_t*)(ws + 34013184);  //    131,072 bf16
    float*    hdec    = ws + 34078720;               //    131,072
    float*    xcat    = ws + 34209792;               //    262,144
    float*    xin     = ws + 34471936;               //    131,072
    float*    gi      = ws + 34603008;               //    393,216
    float*    ghd     = ws + 34996224;               //    393,216
    float*    logits  = ws + 35389440;               //     49,664
    float*    bias2f  = ws + 35439104;               //      1,024
    float*    bias2b  = ws + 35440128;               //      1,024

    ushort_t* xgf_bf = (ushort_t*)buf0;              // (32,512,1024) bf16
    ushort_t* xgb_bf = (ushort_t*)buf0 + 16777216;   // (32,512,1024) bf16
    float*    enc    = buf1;                         // (32,512,256) fp32

    dim3 blk(256);
    const int NOSPLIT = 1 << 30;

    // ---- weight converts ----
    f2b_k<<<2304, blk, 0, stream>>>(conv1_w, c1w_bf, 589824);
    f2b_k<<<2304, blk, 0, stream>>>(conv2_w, c2w_bf, 589824);
    f2b_k<<<1024, blk, 0, stream>>>(wih_f, wihf_bf, 262144);
    f2b_k<<<1024, blk, 0, stream>>>(wih_b, wihb_bf, 262144);
    f2b_k<<<1024, blk, 0, stream>>>(whh_f, whhf_bf, 262144);
    f2b_k<<<1024, blk, 0, stream>>>(whh_b, whhb_bf, 262144);
    f2b_k<<<512,  blk, 0, stream>>>(emb_w, embw_bf, 131072);
    addvec_k<<<4, blk, 0, stream>>>(bih_f, bhh_f, bias2f, 1024);
    addvec_k<<<4, blk, 0, stream>>>(bih_b, bhh_b, bias2b, 1024);

    // ---- CRNN encoder ----
    cgemm_k<<<dim3(2, 512), blk, 0, stream>>>(rois, c1w_bf, buf0, 8, 4);
    gn_relu_k<<<16384, blk, 0, stream>>>(buf0, gn1_s, gn1_b, 128);
    cgemm_k<<<dim3(2, 256), blk, 0, stream>>>(buf0, c2w_bf, buf1, 4, 2);
    gn_relu_k<<<16384, blk, 0, stream>>>(buf1, gn2_s, gn2_b, 64);
    pool_tr_k<<<16384, blk, 0, stream>>>(buf1, xT_bf);

    // ---- LSTM input gates (x @ Wih^T + bias), bf16 out ----
    mgemm_k<1,0><<<dim3(8, 128), blk, 0, stream>>>(xT_bf, wihf_bf, wihf_bf, bias2f,
                                                   nullptr, nullptr, xgf_bf, 16384, 1024, 256, NOSPLIT);
    mgemm_k<1,0><<<dim3(8, 128), blk, 0, stream>>>(xT_bf, wihb_bf, wihb_bf, bias2b,
                                                   nullptr, nullptr, xgb_bf, 16384, 1024, 256, NOSPLIT);

    // ---- merged fwd/bwd recurrent loop (32 sequential steps) ----
    hipMemsetAsync(hS_bf, 0, 262144 * 2, stream);
    hipMemsetAsync(cS,    0, 262144 * 4, stream);
    for (int t = 0; t < TENC; t++) {
        mgemm_k<0,1><<<dim3(8, 8), blk, 0, stream>>>(hS_bf, whhf_bf, whhb_bf, nullptr,
                                                     xgf_bf + (size_t)t * 524288,
                                                     xgb_bf + (size_t)(31 - t) * 524288,
                                                     ghb, 1024, 1024, 256, 512);
        lstm2_cell_k<<<1024, blk, 0, stream>>>(ghb, cS, hS_bf, hcat_bf, t);
    }

    // enc = hcat @ emb_w^T + emb_b
    mgemm_k<0,0><<<dim3(2, 128), blk, 0, stream>>>(hcat_bf, embw_bf, embw_bf, emb_b,
                                                   nullptr, nullptr, enc, 16384, 256, 512, NOSPLIT);

    // ---- attention GRU decoder ----
    hipMemsetAsync(hdec, 0, 131072 * 4, stream);
    float* out = (float*)d_out;
    for (int t = 0; t < TDEC; t++) {
        att_fused_k<<<512, blk, 0, stream>>>(hdec, enc, vat_w, vat_b, targets, att_emb, xcat, t);
        gemm_k<1><<<dim3(4, 8), blk, 0, stream>>>(xcat, comb_w, comb_b, xin, 512, 256, 512);
        gemmz_k<<<dim3(12, 8, 2), blk, 0, stream>>>(xin, gru_wih, gru_bih, gi,
                                                    hdec, gru_whh, gru_bhh, ghd);
        gru_cell_k<<<512, blk, 0, stream>>>(gi, ghd, hdec);
        gemm_k<0><<<dim3(2, 8), blk, 0, stream>>>(hdec, out_w, out_b, logits, 512, VOCC, 256);
        loss_k<<<1, dim3(512), 0, stream>>>(logits, targets, out, t);
    }
}

// Round 3
// 2199.025 us; speedup vs baseline: 4.4118x; 2.6022x over previous
//
#include <hip/hip_runtime.h>
#include <math.h>

#define NROI 512
#define CDIM 256
#define TENC 32
#define TDEC 25
#define VOCC 97

typedef unsigned short ushort_t;
typedef __attribute__((ext_vector_type(8))) short short8v;
typedef __attribute__((ext_vector_type(4))) float float4v;

__device__ __forceinline__ float sigmoidf_(float x){ return 1.f/(1.f+__expf(-x)); }
__device__ __forceinline__ float tanhf_(float x){
    float ax = fminf(fabsf(x), 15.f);
    float e = __expf(2.f * ax);
    float r = (e - 1.f) / (e + 1.f);
    return copysignf(r, x);
}
__device__ __forceinline__ ushort_t f2b(float f){
    unsigned u = __float_as_uint(f);
    u = u + 0x7fffu + ((u >> 16) & 1u);
    return (ushort_t)(u >> 16);
}
__device__ __forceinline__ float b2f(ushort_t h){
    return __uint_as_float(((unsigned)h) << 16);
}

// ---------------------------------------------------------------------------
// One-shot weight conversion / reorder (bf16) + bias merges.
// ---------------------------------------------------------------------------
__global__ void convert_all_k(
    const float* c1s, const float* c2s, const float* wf, const float* wb,
    const float* hf, const float* hb, const float* em, const float* cb,
    const float* gi, const float* gh, const float* ow, const float* ob,
    const float* bif, const float* bhf, const float* bib, const float* bhb,
    ushort_t* d_c1, ushort_t* d_c2, ushort_t* d_wf, ushort_t* d_wb,
    ushort_t* d_hf, ushort_t* d_hb, ushort_t* d_em, ushort_t* d_cb,
    ushort_t* d_gi, ushort_t* d_gh, ushort_t* d_ow, float* d_ob,
    float* d_b2f, float* d_b2b)
{
    int i = blockIdx.x * 256 + threadIdx.x;
    if (i < 589824) {   // conv1 reorder [co][ci][9] -> [co][tap][ci]
        int co = i / 2304, rem = i % 2304, tap = rem >> 8, ci = rem & 255;
        d_c1[i] = f2b(c1s[co * 2304 + ci * 9 + tap]); return;
    }
    i -= 589824;
    if (i < 589824) {
        int co = i / 2304, rem = i % 2304, tap = rem >> 8, ci = rem & 255;
        d_c2[i] = f2b(c2s[co * 2304 + ci * 9 + tap]); return;
    }
    i -= 589824;
    if (i < 262144) { d_wf[i] = f2b(wf[i]); return; }  i -= 262144;
    if (i < 262144) { d_wb[i] = f2b(wb[i]); return; }  i -= 262144;
    if (i < 262144) { d_hf[i] = f2b(hf[i]); return; }  i -= 262144;
    if (i < 262144) { d_hb[i] = f2b(hb[i]); return; }  i -= 262144;
    if (i < 131072) { d_em[i] = f2b(em[i]); return; }  i -= 131072;
    if (i < 131072) { d_cb[i] = f2b(cb[i]); return; }  i -= 131072;
    if (i < 196608) { d_gi[i] = f2b(gi[i]); return; }  i -= 196608;
    if (i < 196608) { d_gh[i] = f2b(gh[i]); return; }  i -= 196608;
    if (i < 32768) {    // out_w padded 97 -> 128 rows
        int r = i >> 8;
        d_ow[i] = (r < VOCC) ? f2b(ow[i - (r << 8) + r * 256]) : 0; return;
    }
    i -= 32768;
    if (i < 128) { d_ob[i] = (i < VOCC) ? ob[i] : 0.f; return; }  i -= 128;
    if (i < 1024) { d_b2f[i] = bif[i] + bhf[i]; return; }  i -= 1024;
    if (i < 1024) { d_b2b[i] = bib[i] + bhb[i]; return; }
}

// rois NCHW fp32 (512,256,8,32) -> R NHWC bf16 (512,8,32,256); LDS transpose
__global__ void nchw2nhwc_k(const float* __restrict__ in, ushort_t* __restrict__ out)
{
    __shared__ float t[64][33];
    int b = blockIdx.x;                 // ((n*8 + h)*4 + cb)
    int cb = b & 3, h = (b >> 2) & 7, n = b >> 5;
    const float* src = in + (((size_t)n * 256 + cb * 64) * 8 + h) * 32;
    int w = threadIdx.x & 31, cr = threadIdx.x >> 5;
    #pragma unroll
    for (int p = 0; p < 8; p++) {
        int c = p * 8 + cr;
        t[c][w] = src[(size_t)c * 256 + w];
    }
    __syncthreads();
    int c2 = threadIdx.x & 63, wr2 = threadIdx.x >> 6;
    ushort_t* dst = out + ((size_t)n * 8 + h) * 32 * 256 + cb * 64;
    #pragma unroll
    for (int q = 0; q < 8; q++) {
        int ww = q * 4 + wr2;
        dst[(size_t)ww * 256 + c2] = f2b(t[c2][ww]);
    }
}

// ---------------------------------------------------------------------------
// MFMA bf16 GEMM body: C[M,N] = act(A[M,K]@B[N,K]^T + bias + bf16 addend)
// 128x128 tile, 256 thr (4 waves 2x2), BK=32, dbuf regs, LDS stride 40.
// ---------------------------------------------------------------------------
template<int OUTBF, int ADDBF, int ACT>
__device__ __forceinline__ void mgemm_body(
    const ushort_t* __restrict__ A, const ushort_t* __restrict__ Ba,
    const ushort_t* __restrict__ Bb, const float* __restrict__ bias,
    const ushort_t* __restrict__ adda, const ushort_t* __restrict__ addb,
    void* __restrict__ Cout, int M, int N, int K, int rowsplit, int bx, int by)
{
    __shared__ ushort_t As[128 * 40];
    __shared__ ushort_t Bs[128 * 40];
    const int tid = threadIdx.x;
    const int lane = tid & 63, wid = tid >> 6;
    const int wr = wid >> 1, wc = wid & 1;
    const int bm = by * 128, bn = bx * 128;
    const ushort_t* Bp = (bm < rowsplit) ? Ba : Bb;

    const int r0 = tid >> 2, c0 = tid & 3;
    const int r1 = r0 + 64;
    const size_t Ar0 = (size_t)(bm + r0) * K, Ar1 = (size_t)(bm + r1) * K;
    const size_t Br0 = (size_t)(bn + r0) * K, Br1 = (size_t)(bn + r1) * K;

    float4v acc[4][4];
    #pragma unroll
    for (int m = 0; m < 4; m++)
        #pragma unroll
        for (int n = 0; n < 4; n++) { float4v z = {0.f,0.f,0.f,0.f}; acc[m][n] = z; }

    short8v ra[2][2], rb[2][2];
    auto LOAD = [&](int b, int k0) {
        ra[b][0] = *(const short8v*)&A [Ar0 + k0 + c0 * 8];
        ra[b][1] = *(const short8v*)&A [Ar1 + k0 + c0 * 8];
        rb[b][0] = *(const short8v*)&Bp[Br0 + k0 + c0 * 8];
        rb[b][1] = *(const short8v*)&Bp[Br1 + k0 + c0 * 8];
    };
    auto STORE = [&](int b) {
        *(short8v*)&As[r0 * 40 + c0 * 8] = ra[b][0];
        *(short8v*)&As[r1 * 40 + c0 * 8] = ra[b][1];
        *(short8v*)&Bs[r0 * 40 + c0 * 8] = rb[b][0];
        *(short8v*)&Bs[r1 * 40 + c0 * 8] = rb[b][1];
    };
    const int lr = lane & 15, lk = lane >> 4;
    auto COMPUTE = [&]() {
        short8v af[4], bf[4];
        #pragma unroll
        for (int m = 0; m < 4; m++)
            af[m] = *(const short8v*)&As[(wr * 64 + m * 16 + lr) * 40 + lk * 8];
        #pragma unroll
        for (int n = 0; n < 4; n++)
            bf[n] = *(const short8v*)&Bs[(wc * 64 + n * 16 + lr) * 40 + lk * 8];
        #pragma unroll
        for (int m = 0; m < 4; m++)
            #pragma unroll
            for (int n = 0; n < 4; n++)
                acc[m][n] = __builtin_amdgcn_mfma_f32_16x16x32_bf16(af[m], bf[n], acc[m][n], 0, 0, 0);
    };

    LOAD(0, 0);
    for (int k0 = 0; k0 < K; k0 += 64) {
        __syncthreads();
        STORE(0);
        __syncthreads();
        LOAD(1, k0 + 32);
        COMPUTE();
        __syncthreads();
        STORE(1);
        __syncthreads();
        if (k0 + 64 < K) LOAD(0, k0 + 64);
        COMPUTE();
    }

    const ushort_t* add = (bm < rowsplit) ? adda : addb;
    const int roff = (bm < rowsplit) ? 0 : rowsplit;
    #pragma unroll
    for (int m = 0; m < 4; m++)
        #pragma unroll
        for (int n = 0; n < 4; n++)
            #pragma unroll
            for (int r = 0; r < 4; r++) {
                int row = bm + wr * 64 + m * 16 + lk * 4 + r;
                int col = bn + wc * 64 + n * 16 + lr;
                float v = acc[m][n][r];
                if (bias) v += bias[col];
                if (ADDBF) v += b2f(add[(size_t)(row - roff) * N + col]);
                if (ACT == 1) v = fmaxf(v, 0.f);
                if (OUTBF) ((ushort_t*)Cout)[(size_t)row * N + col] = f2b(v);
                else       ((float*)   Cout)[(size_t)row * N + col] = v;
            }
}

template<int OUTBF, int ADDBF, int ACT>
__global__ void __launch_bounds__(256, 2)
mgemm_k(const ushort_t* __restrict__ A, const ushort_t* __restrict__ Ba,
        const ushort_t* __restrict__ Bb, const float* __restrict__ bias,
        const ushort_t* __restrict__ adda, const ushort_t* __restrict__ addb,
        void* __restrict__ Cout, int M, int N, int K, int rowsplit)
{
    mgemm_body<OUTBF, ADDBF, ACT>(A, Ba, Bb, bias, adda, addb, Cout, M, N, K,
                                  rowsplit, blockIdx.x, blockIdx.y);
}

// gi / gh in one launch (both M=512, N=768, K=256)
__global__ void __launch_bounds__(256, 2)
mgemm_dual_k(const ushort_t* A0, const ushort_t* B0, const float* b0, float* C0,
             const ushort_t* A1, const ushort_t* B1, const float* b1, float* C1)
{
    const ushort_t* A = blockIdx.z ? A1 : A0;
    const ushort_t* B = blockIdx.z ? B1 : B0;
    const float*   bi = blockIdx.z ? b1 : b0;
    float*          C = blockIdx.z ? C1 : C0;
    mgemm_body<0, 0, 0>(A, B, B, bi, nullptr, nullptr, C, 512, 768, 256,
                        1 << 30, blockIdx.x, blockIdx.y);
}

// ---------------------------------------------------------------------------
// Conv 3x3 stride(2,1) pad(1,1): NHWC bf16 in, reordered weights, NHWC bf16 out.
// M = 512*Hout*32 (row=(n,ho,wo)), N=256, K=2304 ordered (tap, ci).
// ---------------------------------------------------------------------------
__global__ void __launch_bounds__(256, 2)
cgemm_k(const ushort_t* __restrict__ in, const ushort_t* __restrict__ wt,
        ushort_t* __restrict__ out, int Hin, int hmask, int nshift)
{
    const int K = 2304;
    __shared__ ushort_t As[128 * 40];
    __shared__ ushort_t Bs[128 * 40];
    const int tid = threadIdx.x;
    const int lane = tid & 63, wid = tid >> 6;
    const int wr = wid >> 1, wc = wid & 1;
    const int bm = blockIdx.y * 128, bn = blockIdx.x * 128;

    const int r0 = tid >> 2, c0 = tid & 3;
    const int r1 = r0 + 64;
    // chunk row -> (n, ho, wo) decode, hoisted
    const int row0 = bm + r0, row1 = bm + r1;
    const int wo0 = row0 & 31, wo1 = row1 & 31;
    const int hh0 = ((row0 >> 5) & hmask) * 2 - 1, hh1 = ((row1 >> 5) & hmask) * 2 - 1;
    const size_t base0 = (size_t)(row0 >> nshift) * Hin * 32 * 256;
    const size_t base1 = (size_t)(row1 >> nshift) * Hin * 32 * 256;
    const size_t Br0 = (size_t)(bn + r0) * K, Br1 = (size_t)(bn + r1) * K;

    float4v acc[4][4];
    #pragma unroll
    for (int m = 0; m < 4; m++)
        #pragma unroll
        for (int n = 0; n < 4; n++) { float4v z = {0.f,0.f,0.f,0.f}; acc[m][n] = z; }

    short8v ra[2][2], rb[2][2];
    const short8v zv = {0,0,0,0,0,0,0,0};
    auto LOAD = [&](int b, int k0) {
        int tap = k0 >> 8;
        int kh = tap / 3, kw = tap - kh * 3;
        int ci = (k0 & 255) + c0 * 8;
        int hi0 = hh0 + kh, wi0 = wo0 - 1 + kw;
        int hi1 = hh1 + kh, wi1 = wo1 - 1 + kw;
        ra[b][0] = ((unsigned)hi0 < (unsigned)Hin && (unsigned)wi0 < 32u)
                 ? *(const short8v*)&in[base0 + ((size_t)hi0 * 32 + wi0) * 256 + ci] : zv;
        ra[b][1] = ((unsigned)hi1 < (unsigned)Hin && (unsigned)wi1 < 32u)
                 ? *(const short8v*)&in[base1 + ((size_t)hi1 * 32 + wi1) * 256 + ci] : zv;
        rb[b][0] = *(const short8v*)&wt[Br0 + k0 + c0 * 8];
        rb[b][1] = *(const short8v*)&wt[Br1 + k0 + c0 * 8];
    };
    auto STORE = [&](int b) {
        *(short8v*)&As[r0 * 40 + c0 * 8] = ra[b][0];
        *(short8v*)&As[r1 * 40 + c0 * 8] = ra[b][1];
        *(short8v*)&Bs[r0 * 40 + c0 * 8] = rb[b][0];
        *(short8v*)&Bs[r1 * 40 + c0 * 8] = rb[b][1];
    };
    const int lr = lane & 15, lk = lane >> 4;
    auto COMPUTE = [&]() {
        short8v af[4], bf[4];
        #pragma unroll
        for (int m = 0; m < 4; m++)
            af[m] = *(const short8v*)&As[(wr * 64 + m * 16 + lr) * 40 + lk * 8];
        #pragma unroll
        for (int n = 0; n < 4; n++)
            bf[n] = *(const short8v*)&Bs[(wc * 64 + n * 16 + lr) * 40 + lk * 8];
        #pragma unroll
        for (int m = 0; m < 4; m++)
            #pragma unroll
            for (int n = 0; n < 4; n++)
                acc[m][n] = __builtin_amdgcn_mfma_f32_16x16x32_bf16(af[m], bf[n], acc[m][n], 0, 0, 0);
    };

    LOAD(0, 0);
    for (int k0 = 0; k0 < K; k0 += 64) {
        __syncthreads();
        STORE(0);
        __syncthreads();
        LOAD(1, k0 + 32);
        COMPUTE();
        __syncthreads();
        STORE(1);
        __syncthreads();
        if (k0 + 64 < K) LOAD(0, k0 + 64);
        COMPUTE();
    }

    #pragma unroll
    for (int m = 0; m < 4; m++)
        #pragma unroll
        for (int n = 0; n < 4; n++)
            #pragma unroll
            for (int r = 0; r < 4; r++) {
                int row = bm + wr * 64 + m * 16 + lk * 4 + r;
                int col = bn + wc * 64 + n * 16 + lr;
                out[(size_t)row * 256 + col] = f2b(acc[m][n][r]);
            }
}

// block-level mean/rstd reduce helper (256 threads)
__device__ __forceinline__ void gn_stats(float sum, float sq, int len,
                                         float* rs, float* rq, float& mu, float& rstd)
{
    for (int o = 32; o > 0; o >>= 1) { sum += __shfl_down(sum, o); sq += __shfl_down(sq, o); }
    int wid = threadIdx.x >> 6, lane = threadIdx.x & 63;
    if (lane == 0) { rs[wid] = sum; rq[wid] = sq; }
    __syncthreads();
    if (threadIdx.x == 0) {
        float S = rs[0] + rs[1] + rs[2] + rs[3];
        float Q = rq[0] + rq[1] + rq[2] + rq[3];
        float m = S / len;
        rs[4] = m; rq[4] = rsqrtf(Q / len - m * m + 1e-5f);
    }
    __syncthreads();
    mu = rs[4]; rstd = rq[4];
}

// GroupNorm+ReLU on NHWC bf16 (block per (n, g)); HW = Hout*32
__global__ void gn_nhwc_k(const ushort_t* __restrict__ y, ushort_t* __restrict__ x,
                          const float* __restrict__ s, const float* __restrict__ b, int HW)
{
    __shared__ float rs[8], rq[8];
    int blk = blockIdx.x; int g = blk & 31; int n = blk >> 5;
    const ushort_t* p = y + (size_t)n * HW * 256 + g * 8;
    ushort_t* q = x + (size_t)n * HW * 256 + g * 8;
    int len = HW * 8;
    float sum = 0.f, sq = 0.f;
    for (int e = threadIdx.x; e < len; e += 256) {
        int hw = e >> 3, c = e & 7;
        float v = b2f(p[hw * 256 + c]);
        sum += v; sq += v * v;
    }
    float mu, rstd;
    gn_stats(sum, sq, len, rs, rq, mu, rstd);
    for (int e = threadIdx.x; e < len; e += 256) {
        int hw = e >> 3, c = e & 7;
        float v = (b2f(p[hw * 256 + c]) - mu) * rstd * s[g * 8 + c] + b[g * 8 + c];
        q[hw * 256 + c] = f2b(fmaxf(v, 0.f));
    }
}

// GN2 + ReLU + mean-over-H + transpose: y2 NHWC bf16 (512,2,32,256) -> xT (32,512,256)
__global__ void gn_pool_k(const ushort_t* __restrict__ y, ushort_t* __restrict__ xT,
                          const float* __restrict__ s, const float* __restrict__ b)
{
    __shared__ float rs[8], rq[8];
    int blk = blockIdx.x; int g = blk & 31; int n = blk >> 5;
    const ushort_t* p = y + (size_t)n * 64 * 256 + g * 8;
    float sum = 0.f, sq = 0.f;
    for (int e = threadIdx.x; e < 512; e += 256) {
        int hw = e >> 3, c = e & 7;
        float v = b2f(p[hw * 256 + c]);
        sum += v; sq += v * v;
    }
    float mu, rstd;
    gn_stats(sum, sq, 512, rs, rq, mu, rstd);
    int w = threadIdx.x >> 3, c = threadIdx.x & 7;
    float sc = s[g * 8 + c], bb = b[g * 8 + c];
    float v0 = (b2f(p[(size_t)w * 256 + c]) - mu) * rstd * sc + bb;
    float v1 = (b2f(p[(size_t)(32 + w) * 256 + c]) - mu) * rstd * sc + bb;
    float pooled = 0.5f * (fmaxf(v0, 0.f) + fmaxf(v1, 0.f));
    xT[((size_t)w * 512 + n) * 256 + g * 8 + c] = f2b(pooled);
}

// Merged fwd/bwd LSTM cell. ghb (1024,1024) fp32: rows 0-511 fwd@t, 512-1023 bwd@31-t
__global__ void lstm2_cell_k(const float* __restrict__ g, float* __restrict__ cS,
                             ushort_t* __restrict__ hbf, ushort_t* __restrict__ hcat, int t)
{
    int idx = blockIdx.x * 256 + threadIdx.x;
    int n2 = idx >> 8, cc = idx & 255;
    const float* gr = g + (size_t)n2 * 1024;
    float i_ = sigmoidf_(gr[cc]);
    float f_ = sigmoidf_(gr[256 + cc]);
    float g_ = tanhf_(gr[512 + cc]);
    float o_ = sigmoidf_(gr[768 + cc]);
    float cn = f_ * cS[idx] + i_ * g_;
    cS[idx] = cn;
    float hn = o_ * tanhf_(cn);
    ushort_t hb = f2b(hn);
    hbf[idx] = hb;
    if (n2 < 512) hcat[((size_t)t * 512 + n2) * 512 + cc] = hb;
    else          hcat[((size_t)(31 - t) * 512 + (n2 - 512)) * 512 + 256 + cc] = hb;
}

// Fused attention: scores + softmax + ctx + xcat (bf16). Block per roi n.
__global__ void att_fused_k(const float* __restrict__ hdec, const float* __restrict__ enc,
                            const float* __restrict__ vw, const float* __restrict__ vb,
                            const int* __restrict__ targets, const float* __restrict__ att_emb,
                            ushort_t* __restrict__ xcat, int t)
{
    __shared__ float encs[32][256];
    __shared__ float sc[32];
    const int n = blockIdx.x;
    const int tid = threadIdx.x, lane = tid & 63, w = tid >> 6;
    const float* hrow = hdec + n * 256;
    #pragma unroll
    for (int q = 0; q < 8; q++) {
        int tt = w * 8 + q;
        const float* ep = enc + ((size_t)tt * 512 + n) * 256;
        float s = 0.f;
        #pragma unroll
        for (int j = 0; j < 4; j++) {
            int c = lane + j * 64;
            float e = ep[c];
            encs[tt][c] = e;
            s += tanhf_(hrow[c] + e) * vw[c];
        }
        for (int o = 32; o > 0; o >>= 1) s += __shfl_down(s, o);
        if (lane == 0) sc[tt] = s + vb[0];
    }
    __syncthreads();
    float m = -1e30f;
    #pragma unroll
    for (int t2 = 0; t2 < 32; t2++) m = fmaxf(m, sc[t2]);
    float sum = 0.f;
    #pragma unroll
    for (int t2 = 0; t2 < 32; t2++) sum += __expf(sc[t2] - m);
    float ctxv = 0.f;
    #pragma unroll
    for (int t2 = 0; t2 < 32; t2++) ctxv += __expf(sc[t2] - m) * encs[t2][tid];
    ctxv /= sum;
    int tok = (t == 0) ? 0 : targets[n * TDEC + t - 1];
    xcat[(size_t)n * 512 + 256 + tid] = f2b(ctxv);
    xcat[(size_t)n * 512 + tid] = f2b(att_emb[(size_t)tok * 256 + tid]);
}

// GRU cell: h fp32 update + bf16 mirrors + history append
__global__ void gru_cell_k(const float* __restrict__ gi, const float* __restrict__ gh,
                           float* __restrict__ h, ushort_t* __restrict__ h_bf,
                           ushort_t* __restrict__ hist, int t)
{
    int idx = blockIdx.x * 256 + threadIdx.x;
    int n = idx >> 8;
    int cc = idx & 255;
    const float* a = gi + (size_t)n * 768;
    const float* b = gh + (size_t)n * 768;
    float r  = sigmoidf_(a[cc] + b[cc]);
    float z  = sigmoidf_(a[256 + cc] + b[256 + cc]);
    float ng = tanhf_(a[512 + cc] + r * b[512 + cc]);
    float hv = (1.f - z) * ng + z * h[idx];
    h[idx] = hv;
    ushort_t hb = f2b(hv);
    h_bf[idx] = hb;
    hist[(size_t)t * 131072 + idx] = hb;
}

// per-step NLL means from padded logits (12800 x 128); block per t
__global__ void loss_batch_k(const float* __restrict__ logits, const int* __restrict__ targets,
                             float* __restrict__ part)
{
    __shared__ float red[256];
    int t = blockIdx.x;
    float acc = 0.f;
    for (int rr = threadIdx.x; rr < 512; rr += 256) {
        const float* row = logits + ((size_t)t * 512 + rr) * 128;
        float m = -1e30f;
        for (int j = 0; j < VOCC; j++) m = fmaxf(m, row[j]);
        float s2 = 0.f;
        for (int j = 0; j < VOCC; j++) s2 += __expf(row[j] - m);
        int tg = targets[rr * TDEC + t];
        acc += m + __logf(s2) - row[tg];
    }
    red[threadIdx.x] = acc;
    __syncthreads();
    for (int o = 128; o > 0; o >>= 1) {
        if (threadIdx.x < o) red[threadIdx.x] += red[threadIdx.x + o];
        __syncthreads();
    }
    if (threadIdx.x == 0) part[t] = red[0] / 512.f;
}

__global__ void loss_final_k(const float* __restrict__ part, float* __restrict__ out)
{
    if (threadIdx.x == 0) {
        float s = 0.f;
        for (int t = 0; t < TDEC; t++) s += part[t];
        out[0] = s;
    }
}

extern "C" void kernel_launch(void* const* d_in, const int* in_sizes, int n_in,
                              void* d_out, int out_size, void* d_ws, size_t ws_size,
                              hipStream_t stream)
{
    const float* rois     = (const float*)d_in[0];
    const int*   targets  = (const int*)  d_in[1];
    const float* conv1_w  = (const float*)d_in[2];
    const float* gn1_s    = (const float*)d_in[3];
    const float* gn1_b    = (const float*)d_in[4];
    const float* conv2_w  = (const float*)d_in[5];
    const float* gn2_s    = (const float*)d_in[6];
    const float* gn2_b    = (const float*)d_in[7];
    const float* wih_f    = (const float*)d_in[8];
    const float* whh_f    = (const float*)d_in[9];
    const float* bih_f    = (const float*)d_in[10];
    const float* bhh_f    = (const float*)d_in[11];
    const float* wih_b    = (const float*)d_in[12];
    const float* whh_b    = (const float*)d_in[13];
    const float* bih_b    = (const float*)d_in[14];
    const float* bhh_b    = (const float*)d_in[15];
    const float* emb_w    = (const float*)d_in[16];
    const float* emb_b    = (const float*)d_in[17];
    const float* att_emb  = (const float*)d_in[18];
    const float* comb_w   = (const float*)d_in[19];
    const float* comb_b   = (const float*)d_in[20];
    const float* gru_wih  = (const float*)d_in[21];
    const float* gru_whh  = (const float*)d_in[22];
    const float* gru_bih  = (const float*)d_in[23];
    const float* gru_bhh  = (const float*)d_in[24];
    const float* out_w    = (const float*)d_in[25];
    const float* out_b    = (const float*)d_in[26];
    const float* vat_w    = (const float*)d_in[27];
    const float* vat_b    = (const float*)d_in[28];

    float* ws = (float*)d_ws;
    // Regions (float offsets), total 35,014,784 floats = 140.1 MB
    const size_t REG1 = 0;              // 16,777,216: R (rois NHWC bf16) | xgf+xgb bf16
    const size_t REG2 = 16777216;       //  8,388,608: Y1b | Y2b+xT | hcat+ghb+hS+cS | dec temps+enc
    const size_t REG3 = 25165824;       //  8,388,608: X1b | hist+logits_all+loss_part
    const size_t WREG = 33554432;       //  1,460,352: converted weights

    ushort_t* R      = (ushort_t*)(ws + REG1);
    ushort_t* xgf    = (ushort_t*)(ws + REG1);                 // (32,512,1024)
    ushort_t* xgb    = (ushort_t*)(ws + REG1 + 8388608);
    ushort_t* Y1b    = (ushort_t*)(ws + REG2);                 // (65536,256)
    ushort_t* Y2b    = (ushort_t*)(ws + REG2);                 // (32768,256)
    ushort_t* xT     = (ushort_t*)(ws + REG2 + 4194304);       // (32,512,256)
    ushort_t* hcat   = (ushort_t*)(ws + REG2);                 // (16384,512)
    float*    ghb    = ws + REG2 + 2097152;                    // (1024,1024)
    ushort_t* hS_bf  = (ushort_t*)(ws + REG2 + 3145728);       // (1024,256)
    float*    cS     = ws + REG2 + 3276800;                    // (1024,256)
    float*    enc    = ws + REG2 + 4194304;                    // (32,512,256)
    // decoder temps (REG2 low half, after hcat/ghb dead)
    float*    hdec   = ws + REG2;                              // 131072
    ushort_t* hdec_bf= (ushort_t*)(ws + REG2 + 131072);        // 65536 slots
    ushort_t* xcat_bf= (ushort_t*)(ws + REG2 + 196608);        // 131072 slots
    ushort_t* xin_bf = (ushort_t*)(ws + REG2 + 327680);        // 65536 slots
    float*    gi     = ws + REG2 + 393216;                     // (512,768)
    float*    ghd    = ws + REG2 + 786432;                     // (512,768)
    ushort_t* X1b    = (ushort_t*)(ws + REG3);                 // (16384? (512,4,32,256))
    ushort_t* hist   = (ushort_t*)(ws + REG3);                 // (25,512,256) bf16
    float*    logitsA= ws + REG3 + 1638400;                    // (12800,128)
    float*    lpart  = ws + REG3 + 3276800;                    // 25

    ushort_t* c1w  = (ushort_t*)(ws + WREG);
    ushort_t* c2w  = (ushort_t*)(ws + WREG + 294912);
    ushort_t* wihf = (ushort_t*)(ws + WREG + 589824);
    ushort_t* wihb = (ushort_t*)(ws + WREG + 720896);
    ushort_t* whhf = (ushort_t*)(ws + WREG + 851968);
    ushort_t* whhb = (ushort_t*)(ws + WREG + 983040);
    ushort_t* embw = (ushort_t*)(ws + WREG + 1114112);
    ushort_t* combw= (ushort_t*)(ws + WREG + 1179648);
    ushort_t* gwih = (ushort_t*)(ws + WREG + 1245184);
    ushort_t* gwhh = (ushort_t*)(ws + WREG + 1343488);
    ushort_t* outw = (ushort_t*)(ws + WREG + 1441792);
    float*    outb = ws + WREG + 1458176;
    float*    bias2f = ws + WREG + 1458304;
    float*    bias2b = ws + WREG + 1459328;

    dim3 blk(256);
    const int NOSPLIT = 1 << 30;

    convert_all_k<<<11402, blk, 0, stream>>>(
        conv1_w, conv2_w, wih_f, wih_b, whh_f, whh_b, emb_w, comb_w,
        gru_wih, gru_whh, out_w, out_b, bih_f, bhh_f, bih_b, bhh_b,
        c1w, c2w, wihf, wihb, whhf, whhb, embw, combw, gwih, gwhh,
        outw, outb, bias2f, bias2b);

    // ---- encoder ----
    nchw2nhwc_k<<<16384, blk, 0, stream>>>(rois, R);
    cgemm_k<<<dim3(2, 512), blk, 0, stream>>>(R, c1w, Y1b, 8, 3, 7);
    gn_nhwc_k<<<16384, blk, 0, stream>>>(Y1b, X1b, gn1_s, gn1_b, 128);
    cgemm_k<<<dim3(2, 256), blk, 0, stream>>>(X1b, c2w, Y2b, 4, 1, 6);
    gn_pool_k<<<16384, blk, 0, stream>>>(Y2b, xT, gn2_s, gn2_b);

    // ---- LSTM input gates ----
    mgemm_k<1,0,0><<<dim3(8, 128), blk, 0, stream>>>(xT, wihf, wihf, bias2f,
        nullptr, nullptr, xgf, 16384, 1024, 256, NOSPLIT);
    mgemm_k<1,0,0><<<dim3(8, 128), blk, 0, stream>>>(xT, wihb, wihb, bias2b,
        nullptr, nullptr, xgb, 16384, 1024, 256, NOSPLIT);

    // ---- merged fwd/bwd recurrent loop ----
    hipMemsetAsync(hS_bf, 0, 1024 * 256 * 2, stream);
    hipMemsetAsync(cS,    0, 1024 * 256 * 4, stream);
    for (int t = 0; t < TENC; t++) {
        mgemm_k<0,1,0><<<dim3(8, 8), blk, 0, stream>>>(hS_bf, whhf, whhb, nullptr,
            xgf + (size_t)t * 524288, xgb + (size_t)(31 - t) * 524288,
            ghb, 1024, 1024, 256, 512);
        lstm2_cell_k<<<1024, blk, 0, stream>>>(ghb, cS, hS_bf, hcat, t);
    }

    // enc = hcat @ emb_w^T + emb_b
    mgemm_k<0,0,0><<<dim3(2, 128), blk, 0, stream>>>(hcat, embw, embw, emb_b,
        nullptr, nullptr, enc, 16384, 256, 512, NOSPLIT);

    // ---- attention GRU decoder ----
    hipMemsetAsync(hdec, 0, 131072 * 4, stream);
    hipMemsetAsync(hdec_bf, 0, 131072 * 2, stream);
    for (int t = 0; t < TDEC; t++) {
        att_fused_k<<<512, blk, 0, stream>>>(hdec, enc, vat_w, vat_b, targets, att_emb, xcat_bf, t);
        mgemm_k<1,0,1><<<dim3(2, 4), blk, 0, stream>>>(xcat_bf, combw, combw, comb_b,
            nullptr, nullptr, xin_bf, 512, 256, 512, NOSPLIT);
        mgemm_dual_k<<<dim3(6, 4, 2), blk, 0, stream>>>(xin_bf, gwih, gru_bih, gi,
                                                        hdec_bf, gwhh, gru_bhh, ghd);
        gru_cell_k<<<512, blk, 0, stream>>>(gi, ghd, hdec, hdec_bf, hist, t);
    }

    // ---- deferred output projection + loss ----
    mgemm_k<0,0,0><<<dim3(1, 100), blk, 0, stream>>>(hist, outw, outw, outb,
        nullptr, nullptr, logitsA, 12800, 128, 256, NOSPLIT);
    loss_batch_k<<<TDEC, blk, 0, stream>>>(logitsA, targets, lpart);
    loss_final_k<<<1, dim3(64), 0, stream>>>(lpart, (float*)d_out);
}